// Round 6
// baseline (4171.678 us; speedup 1.0000x reference)
//
#include <hip/hip_runtime.h>

#define DB 512
#define DT 26
#define DF 2048
#define DH 1024
#define DG 4096
#define DC 22
#define NBLK 256
#define LRP 1040   // panel LDS row: 1024 + 16 u16 pad

typedef unsigned short u16;
typedef u16 u16x8 __attribute__((ext_vector_type(8)));
typedef __bf16 bf16x8 __attribute__((ext_vector_type(8)));
typedef float f32x4 __attribute__((ext_vector_type(4)));

__device__ __forceinline__ float sigm(float x) { return 1.f / (1.f + __expf(-x)); }

__device__ __forceinline__ u16 f2b(float v) {
  unsigned u = __float_as_uint(v);
  return (u16)((u + 0x7FFFu + ((u >> 16) & 1u)) >> 16);
}
__device__ __forceinline__ float b2f(u16 h) {
  return __uint_as_float(((unsigned)h) << 16);
}
__device__ __forceinline__ void store_b4(u16* __restrict__ d, size_t o, float4 v) {
  ushort4 s;
  s.x = f2b(v.x); s.y = f2b(v.y); s.z = f2b(v.z); s.w = f2b(v.w);
  *(ushort4*)(d + o) = s;
}

// ---------- device-wide barrier (requires all NBLK blocks resident: 1/CU via LDS) ----------
__device__ __forceinline__ void gridbar(int* __restrict__ cnt, int* __restrict__ gen) {
  __syncthreads();                      // all block threads done (incl. vmcnt drain)
  if (threadIdx.x == 0) {
    __threadfence();                    // release: flush this XCD's dirty L2 to L3
    int g = __hip_atomic_load(gen, __ATOMIC_RELAXED, __HIP_MEMORY_SCOPE_AGENT);
    int old = __hip_atomic_fetch_add(cnt, 1, __ATOMIC_ACQ_REL, __HIP_MEMORY_SCOPE_AGENT);
    if (old == NBLK - 1) {
      __hip_atomic_store(cnt, 0, __ATOMIC_RELAXED, __HIP_MEMORY_SCOPE_AGENT);
      __hip_atomic_store(gen, g + 1, __ATOMIC_RELEASE, __HIP_MEMORY_SCOPE_AGENT);
    } else {
      while (__hip_atomic_load(gen, __ATOMIC_ACQUIRE, __HIP_MEMORY_SCOPE_AGENT) == g)
        __builtin_amdgcn_s_sleep(8);
    }
    __threadfence();                    // acquire: invalidate L1/L2 for fresh reads
  }
  __syncthreads();
}

// ---------- big parallel GEMM (round-4 proven: bm-fastest swizzle, plain stores) ----------
template <int OUTBF>
__global__ __launch_bounds__(256) void gemm_bt(
    const u16* __restrict__ A1, long lda1, int K1,
    const u16* __restrict__ A2, long lda2,
    const u16* __restrict__ B, long ldb, const float* __restrict__ bias,
    void* __restrict__ Cp, long ldc, int M, int N, int K)
{
  constexpr int LR = 72;
  __shared__ __align__(16) u16 sA[64 * LR];
  __shared__ __align__(16) u16 sB[128 * LR];
  const int tid = threadIdx.x, lane = tid & 63;
  const int wid = tid >> 6, wm = wid >> 1, wn = wid & 1;
  const int nbm = M >> 6;
  const int cpx = gridDim.x >> 3;
  const int swz = (blockIdx.x & 7) * cpx + (blockIdx.x >> 3);
  const int bn = swz / nbm, bm = swz % nbm;      // bm fastest (round-4 proven)
  const size_t m0 = (size_t)bm << 6, n0 = (size_t)bn << 7;

  const int row = tid >> 3, c8 = tid & 7;
  u16x8 ra[2], rb[4];

  auto loadA = [&](int k0) {
    const u16* p; long lda; int kk;
    if (k0 < K1) { p = A1; lda = lda1; kk = k0; }
    else         { p = A2; lda = lda2; kk = k0 - K1; }
#pragma unroll
    for (int r = 0; r < 2; ++r)
      ra[r] = *(const u16x8*)(p + (m0 + row + r * 32) * (size_t)lda + (size_t)(kk + c8 * 8));
  };
  auto loadB = [&](int k0) {
#pragma unroll
    for (int r = 0; r < 4; ++r)
      rb[r] = *(const u16x8*)(B + (n0 + row + r * 32) * (size_t)ldb + (size_t)(k0 + c8 * 8));
  };
  loadA(0);
  loadB(0);

  f32x4 acc[2][4] = {};
  for (int k0 = 0; k0 < K; k0 += 64) {
    __syncthreads();
#pragma unroll
    for (int r = 0; r < 2; ++r) *(u16x8*)(sA + (row + r * 32) * LR + c8 * 8) = ra[r];
#pragma unroll
    for (int r = 0; r < 4; ++r) *(u16x8*)(sB + (row + r * 32) * LR + c8 * 8) = rb[r];
    __syncthreads();
    if (k0 + 64 < K) { loadA(k0 + 64); loadB(k0 + 64); }
#pragma unroll
    for (int ks = 0; ks < 2; ++ks) {
      const int ko = ks * 32 + (lane >> 4) * 8;
      bf16x8 af[2], bfr[4];
#pragma unroll
      for (int mi = 0; mi < 2; ++mi)
        af[mi] = *(const bf16x8*)(sA + ((wm << 5) + (mi << 4) + (lane & 15)) * LR + ko);
#pragma unroll
      for (int ni = 0; ni < 4; ++ni)
        bfr[ni] = *(const bf16x8*)(sB + ((wn << 6) + (ni << 4) + (lane & 15)) * LR + ko);
#pragma unroll
      for (int mi = 0; mi < 2; ++mi)
#pragma unroll
        for (int ni = 0; ni < 4; ++ni)
          acc[mi][ni] = __builtin_amdgcn_mfma_f32_16x16x32_bf16(af[mi], bfr[ni], acc[mi][ni], 0, 0, 0);
    }
  }

#pragma unroll
  for (int mi = 0; mi < 2; ++mi) {
    const int row0 = (wm << 5) + (mi << 4) + ((lane >> 4) << 2);
#pragma unroll
    for (int ni = 0; ni < 4; ++ni) {
      const size_t gn = n0 + (size_t)((wn << 6) + (ni << 4) + (lane & 15));
      const float bv = bias[gn];
#pragma unroll
      for (int r = 0; r < 4; ++r) {
        const size_t gm = m0 + (size_t)(row0 + r);
        const float v = acc[mi][ni][r] + bv;
        if (OUTBF) ((u16*)Cp)[gm * (size_t)ldc + gn] = f2b(v);
        else       ((float*)Cp)[gm * (size_t)ldc + gn] = v;
      }
    }
  }
}

// ---------- persistent encoder: panel staged once, c in registers, 1 barrier/step ----------
__global__ __launch_bounds__(512) void enc_persist(
    const u16* __restrict__ W,     // eWh [4096][1024] permuted rows
    const u16* __restrict__ xg,    // encXg rows (b*26+t) x 4096
    u16* __restrict__ H,           // [26][512][1024] bf16
    int* __restrict__ cnt, int* __restrict__ gen)
{
  __shared__ __align__(16) u16 sB[64 * LRP];
  const int tid = threadIdx.x, lane = tid & 63, w = tid >> 6;
  const int nblk = blockIdx.x >> 2, mg = blockIdx.x & 3;
  const int n0 = nblk << 6;
  const int l15 = lane & 15, l4 = lane >> 4;
  const int arow = mg * 128 + (w << 4) + l15;
  const int kof = l4 * 8;
  const int hg = (nblk << 4) | l15;
  const int row0 = mg * 128 + (w << 4) + (l4 << 2);

#pragma unroll
  for (int i = 0; i < 16; ++i) {           // stage 64x1024 weight panel once (128 KB)
    const int c = i * 512 + tid, r = c >> 7, cc = c & 127;
    *(u16x8*)(sB + r * LRP + cc * 8) = *(const u16x8*)(W + (size_t)(n0 + r) * 1024 + cc * 8);
  }
  __syncthreads();

  f32x4 creg = {0.f, 0.f, 0.f, 0.f};
  for (int t = 0; t < DT; ++t) {
    f32x4 acc[4] = {};
    if (t > 0) {
      const u16* Ap = H + (size_t)(t - 1) * DB * DH + (size_t)arow * DH + kof;
      bf16x8 af = *(const bf16x8*)Ap;
      for (int ko = 0; ko < 1024; ko += 32) {
        bf16x8 afn = af;
        if (ko + 32 < 1024) afn = *(const bf16x8*)(Ap + ko + 32);
        bf16x8 b0 = *(const bf16x8*)(sB + (l15)      * LRP + ko + kof);
        bf16x8 b1 = *(const bf16x8*)(sB + (16 + l15) * LRP + ko + kof);
        bf16x8 b2 = *(const bf16x8*)(sB + (32 + l15) * LRP + ko + kof);
        bf16x8 b3 = *(const bf16x8*)(sB + (48 + l15) * LRP + ko + kof);
        acc[0] = __builtin_amdgcn_mfma_f32_16x16x32_bf16(af, b0, acc[0], 0, 0, 0);
        acc[1] = __builtin_amdgcn_mfma_f32_16x16x32_bf16(af, b1, acc[1], 0, 0, 0);
        acc[2] = __builtin_amdgcn_mfma_f32_16x16x32_bf16(af, b2, acc[2], 0, 0, 0);
        acc[3] = __builtin_amdgcn_mfma_f32_16x16x32_bf16(af, b3, acc[3], 0, 0, 0);
        af = afn;
      }
    }
    u16* Hw = H + (size_t)t * DB * DH;
#pragma unroll
    for (int r = 0; r < 4; ++r) {
      const int gm = row0 + r;
      const u16* xr = xg + ((size_t)gm * DT + t) * DG + n0 + l15;
      const float gi = acc[0][r] + b2f(xr[0]);
      const float gf = acc[1][r] + b2f(xr[16]);
      const float gg = acc[2][r] + b2f(xr[32]);
      const float go = acc[3][r] + b2f(xr[48]);
      const float cn = sigm(gf) * creg[r] + sigm(gi) * tanhf(gg);
      creg[r] = cn;
      Hw[(size_t)gm * DH + hg] = f2b(sigm(go) * tanhf(cn));
    }
    if (t < DT - 1) gridbar(cnt, gen);
  }
}

// ---------- persistent decoder: attn+cls phase, 2-phase restaged gemm, cell; 2 barriers/step ----------
__global__ __launch_bounds__(512) void dec_persist(
    const u16* __restrict__ W,        // dWah [4096][2048] permuted (attn-cols | h-cols)
    const u16* __restrict__ xg,       // decXg rows (b*26+t) x 4096
    const u16* __restrict__ projH,    // [26*512][1024] bf16, row = t*512+b
    u16* __restrict__ Z0, u16* __restrict__ Z1,   // [512][2048]: attn | h
    const float* __restrict__ clsW, const float* __restrict__ clsb,
    float* __restrict__ out, int* __restrict__ cnt, int* __restrict__ gen)
{
  __shared__ __align__(16) u16 sB[64 * LRP];
  __shared__ float red[2][DT][4];
  __shared__ float redc[2][DC][4];
  __shared__ float wgt[2][DT];
  const int tid = threadIdx.x, lane = tid & 63, w = tid >> 6;
  const int nblk = blockIdx.x >> 2, mg = blockIdx.x & 3;
  const int n0 = nblk << 6;
  const int l15 = lane & 15, l4 = lane >> 4;
  const int arow = mg * 128 + (w << 4) + l15;
  const int kof = l4 * 8;
  const int hg = (nblk << 4) | l15;
  const int row0 = mg * 128 + (w << 4) + (l4 << 2);
  const int rr = tid >> 8, t4 = tid & 255, wv = (tid >> 6) & 3;
  const int b = 2 * blockIdx.x + rr;

  f32x4 creg = {0.f, 0.f, 0.f, 0.f};
  for (int t = 0; t < DT; ++t) {
    u16* Zin  = (t & 1) ? Z1 : Z0;
    u16* Zout = (t & 1) ? Z0 : Z1;

    // ---- attention (h = Zin.h) + classifier(t-1) ----
    ushort4 hz = *(const ushort4*)(Zin + ((size_t)b << 11) + 1024 + t4 * 4);
    float4 hv = make_float4(b2f(hz.x), b2f(hz.y), b2f(hz.z), b2f(hz.w));
    ushort4 ph[DT];
    float pp[DT];
#pragma unroll
    for (int tt = 0; tt < DT; ++tt) {
      ph[tt] = *(const ushort4*)(projH + (((size_t)tt * DB + b) << 10) + t4 * 4);
      pp[tt] = hv.x * b2f(ph[tt].x) + hv.y * b2f(ph[tt].y) +
               hv.z * b2f(ph[tt].z) + hv.w * b2f(ph[tt].w);
    }
#pragma unroll
    for (int tt = 0; tt < DT; ++tt) {
      float v = pp[tt];
#pragma unroll
      for (int off = 32; off; off >>= 1) v += __shfl_xor(v, off);
      if (lane == 0) red[rr][tt][wv] = v;
    }
    if (t > 0) {
#pragma unroll
      for (int c = 0; c < DC; ++c) {
        const float4 wc = *(const float4*)(clsW + ((size_t)c << 10) + t4 * 4);
        float v = hv.x * wc.x + hv.y * wc.y + hv.z * wc.z + hv.w * wc.w;
#pragma unroll
        for (int off = 32; off; off >>= 1) v += __shfl_xor(v, off);
        if (lane == 0) redc[rr][c][wv] = v;
      }
    }
    __syncthreads();
    if (t4 == 0) {
      float lg[DT], mx = -1e30f;
#pragma unroll
      for (int tt = 0; tt < DT; ++tt) {
        lg[tt] = (red[rr][tt][0] + red[rr][tt][1] + red[rr][tt][2] + red[rr][tt][3]) * 0.03125f;
        mx = fmaxf(mx, lg[tt]);
      }
      float s = 0.f;
#pragma unroll
      for (int tt = 0; tt < DT; ++tt) { lg[tt] = __expf(lg[tt] - mx); s += lg[tt]; }
      const float inv = 1.f / s;
#pragma unroll
      for (int tt = 0; tt < DT; ++tt) wgt[rr][tt] = lg[tt] * inv;
    }
    __syncthreads();
    if (t > 0 && t4 < DC)
      out[((size_t)b * DT + (t - 1)) * DC + t4] =
          redc[rr][t4][0] + redc[rr][t4][1] + redc[rr][t4][2] + redc[rr][t4][3] + clsb[t4];
    float4 a = make_float4(0, 0, 0, 0);
#pragma unroll
    for (int tt = 0; tt < DT; ++tt) {
      const float wt = wgt[rr][tt];
      a.x += wt * b2f(ph[tt].x); a.y += wt * b2f(ph[tt].y);
      a.z += wt * b2f(ph[tt].z); a.w += wt * b2f(ph[tt].w);
    }
    store_b4(Zin, ((size_t)b << 11) + t4 * 4, a);
    gridbar(cnt, gen);                          // attn visible to all blocks

    // ---- gemm: phase 0 over attn-cols, phase 1 over h-cols ----
    f32x4 acc[4] = {};
    for (int phx = 0; phx < 2; ++phx) {
      if (phx == 1 && t == 0) break;            // h_{-1} == 0
      if (!(t == 1 && phx == 0)) {              // t==1 phase0 panel survived t==0
        if (phx) __syncthreads();
#pragma unroll
        for (int i = 0; i < 16; ++i) {
          const int c = i * 512 + tid, r = c >> 7, cc = c & 127;
          *(u16x8*)(sB + r * LRP + cc * 8) =
              *(const u16x8*)(W + (size_t)(n0 + r) * 2048 + phx * 1024 + cc * 8);
        }
        __syncthreads();
      }
      const u16* Ap = Zin + (size_t)arow * 2048 + phx * 1024 + kof;
      bf16x8 af = *(const bf16x8*)Ap;
      for (int ko = 0; ko < 1024; ko += 32) {
        bf16x8 afn = af;
        if (ko + 32 < 1024) afn = *(const bf16x8*)(Ap + ko + 32);
        bf16x8 b0 = *(const bf16x8*)(sB + (l15)      * LRP + ko + kof);
        bf16x8 b1 = *(const bf16x8*)(sB + (16 + l15) * LRP + ko + kof);
        bf16x8 b2 = *(const bf16x8*)(sB + (32 + l15) * LRP + ko + kof);
        bf16x8 b3 = *(const bf16x8*)(sB + (48 + l15) * LRP + ko + kof);
        acc[0] = __builtin_amdgcn_mfma_f32_16x16x32_bf16(af, b0, acc[0], 0, 0, 0);
        acc[1] = __builtin_amdgcn_mfma_f32_16x16x32_bf16(af, b1, acc[1], 0, 0, 0);
        acc[2] = __builtin_amdgcn_mfma_f32_16x16x32_bf16(af, b2, acc[2], 0, 0, 0);
        acc[3] = __builtin_amdgcn_mfma_f32_16x16x32_bf16(af, b3, acc[3], 0, 0, 0);
        af = afn;
      }
    }
#pragma unroll
    for (int r = 0; r < 4; ++r) {
      const int gm = row0 + r;
      const u16* xr = xg + ((size_t)gm * DT + t) * DG + n0 + l15;
      const float gi = acc[0][r] + b2f(xr[0]);
      const float gf = acc[1][r] + b2f(xr[16]);
      const float gg = acc[2][r] + b2f(xr[32]);
      const float go = acc[3][r] + b2f(xr[48]);
      const float cn = sigm(gf) * creg[r] + sigm(gi) * tanhf(gg);
      creg[r] = cn;
      Zout[((size_t)gm << 11) + 1024 + hg] = f2b(sigm(go) * tanhf(cn));
    }
    gridbar(cnt, gen);                          // h_t visible before next attn
  }

  // final classifier on h_25 (DT even -> lives in Z0)
  {
    ushort4 hz = *(const ushort4*)(Z0 + ((size_t)b << 11) + 1024 + t4 * 4);
    float4 hv = make_float4(b2f(hz.x), b2f(hz.y), b2f(hz.z), b2f(hz.w));
#pragma unroll
    for (int c = 0; c < DC; ++c) {
      const float4 wc = *(const float4*)(clsW + ((size_t)c << 10) + t4 * 4);
      float v = hv.x * wc.x + hv.y * wc.y + hv.z * wc.z + hv.w * wc.w;
#pragma unroll
      for (int off = 32; off; off >>= 1) v += __shfl_xor(v, off);
      if (lane == 0) redc[rr][c][wv] = v;
    }
    __syncthreads();
    if (t4 < DC)
      out[((size_t)b * DT + (DT - 1)) * DC + t4] =
          redc[rr][t4][0] + redc[rr][t4][1] + redc[rr][t4][2] + redc[rr][t4][3] + clsb[t4];
  }
}

// ---------- packers ----------
__global__ __launch_bounds__(256) void cvt4_kernel(const float* __restrict__ src,
    u16* __restrict__ dst, int n4) {
  for (int i = blockIdx.x * 256 + threadIdx.x; i < n4; i += gridDim.x * 256) {
    float4 v = *(const float4*)(src + (size_t)i * 4);
    store_b4(dst, (size_t)i * 4, v);
  }
}

__global__ __launch_bounds__(256) void pack_perm_kernel(const float* __restrict__ src,
    long ld_src, long scol, int cols4, u16* __restrict__ dst, long ld_dst, long dcol) {
  const int total = DG * cols4;
  for (int i = blockIdx.x * 256 + threadIdx.x; i < total; i += gridDim.x * 256) {
    const int np = i / cols4, c4 = i - np * cols4;
    const int g = (np >> 4) & 3, h = ((np >> 6) << 4) | (np & 15);
    const int n = g * 1024 + h;
    float4 v = *(const float4*)(src + (size_t)n * ld_src + scol + (size_t)c4 * 4);
    store_b4(dst, (size_t)np * ld_dst + dcol + (size_t)c4 * 4, v);
  }
}

__global__ void pack_bias_perm_kernel(const float* __restrict__ a,
    const float* __restrict__ b, float* __restrict__ o) {
  int np = blockIdx.x * 256 + threadIdx.x;
  if (np < DG) {
    const int g = (np >> 4) & 3, h = ((np >> 6) << 4) | (np & 15);
    const int n = g * 1024 + h;
    o[np] = a[n] + b[n];
  }
}

extern "C" void kernel_launch(void* const* d_in, const int* in_sizes, int n_in,
                              void* d_out, int out_size, void* d_ws, size_t ws_size,
                              hipStream_t stream) {
  const float* x    = (const float*)d_in[0];
  const float* eWih = (const float*)d_in[1];
  const float* eWhh = (const float*)d_in[2];
  const float* ebih = (const float*)d_in[3];
  const float* ebhh = (const float*)d_in[4];
  const float* pW   = (const float*)d_in[5];
  const float* pb   = (const float*)d_in[6];
  const float* dWih = (const float*)d_in[7];
  const float* dWhh = (const float*)d_in[8];
  const float* dbih = (const float*)d_in[9];
  const float* dbhh = (const float*)d_in[10];
  const float* clsW = (const float*)d_in[11];
  const float* clsb = (const float*)d_in[12];
  float* out = (float*)d_out;

  char* p = (char*)d_ws;
  auto alloc = [&](size_t bytes) -> void* {
    char* r = p; p += (bytes + 255) & ~(size_t)255; return (void*)r;
  };
  u16* Xb    = (u16*)alloc((size_t)DB * DT * DF * 2);        // 54.5 MB (reused as projHb)
  u16* eWx   = (u16*)alloc((size_t)DG * 2048 * 2);
  u16* eWh   = (u16*)alloc((size_t)DG * 1024 * 2);
  u16* dWx   = (u16*)alloc((size_t)DG * 2048 * 2);
  u16* dWah  = (u16*)alloc((size_t)DG * 2048 * 2);
  u16* pWb   = (u16*)alloc((size_t)DH * DH * 2);
  u16* Hb    = (u16*)alloc((size_t)DT * DB * DH * 2);
  u16* encXg = (u16*)alloc((size_t)DB * DT * DG * 2);        // 109 MB
  u16* decXg = (u16*)alloc((size_t)DB * DT * DG * 2);        // 109 MB
  u16* Z0    = (u16*)alloc((size_t)DB * 2048 * 2);
  u16* Z1    = (u16*)alloc((size_t)DB * 2048 * 2);
  float* ebs = (float*)alloc(DG * 4);
  float* dbs = (float*)alloc(DG * 4);
  int* bar   = (int*)alloc(256);
  u16* projHb = Xb;                                          // alias: Xb dead after decXg

  // ---- init / pack ----
  hipMemsetAsync(bar, 0, 256, stream);
  hipMemsetAsync(Z0, 0, (size_t)DB * 2048 * 2, stream);
  cvt4_kernel<<<2048, 256, 0, stream>>>(x, Xb, (int)((size_t)DB * DT * DF / 4));
  pack_perm_kernel<<<2048, 256, 0, stream>>>(eWih, DF, 0, DF / 4, eWx, 2048, 0);
  pack_perm_kernel<<<2048, 256, 0, stream>>>(eWhh, DH, 0, DH / 4, eWh, 1024, 0);
  pack_perm_kernel<<<2048, 256, 0, stream>>>(dWih, 3072, 0, DF / 4, dWx, 2048, 0);
  pack_perm_kernel<<<2048, 256, 0, stream>>>(dWih, 3072, 2048, DH / 4, dWah, 2048, 0);
  pack_perm_kernel<<<2048, 256, 0, stream>>>(dWhh, DH, 0, DH / 4, dWah, 2048, 1024);
  cvt4_kernel<<<1024, 256, 0, stream>>>(pW, pWb, DH * DH / 4);
  pack_bias_perm_kernel<<<16, 256, 0, stream>>>(ebih, ebhh, ebs);
  pack_bias_perm_kernel<<<16, 256, 0, stream>>>(dbih, dbhh, dbs);

  // ---- hoisted x-gate GEMMs ----
  gemm_bt<1><<<6656, 256, 0, stream>>>(
      Xb, DF, DF, Xb, DF, eWx, DF, ebs, encXg, DG, DB * DT, DG, DF);
  gemm_bt<1><<<6656, 256, 0, stream>>>(
      Xb, DF, DF, Xb, DF, dWx, DF, dbs, decXg, DG, DB * DT, DG, DF);

  // ---- persistent encoder (26 steps, 1 launch) ----
  enc_persist<<<NBLK, 512, 0, stream>>>(eWh, encXg, Hb, bar, bar + 64);

  // ---- projection of all encoder states ----
  gemm_bt<1><<<1664, 256, 0, stream>>>(
      Hb, DH, DH, Hb, DH, pWb, DH, pb, projHb, DH, DT * DB, DH, DH);

  // ---- persistent decoder (26 steps + final cls, 1 launch) ----
  dec_persist<<<NBLK, 512, 0, stream>>>(
      dWah, decXg, projHb, Z0, Z1, clsW, clsb, out, bar, bar + 64);
}

// Round 7
// 3283.402 us; speedup vs baseline: 1.2705x; 1.2705x over previous
//
#include <hip/hip_runtime.h>

#define DB 512
#define DT 26
#define DF 2048
#define DH 1024
#define DG 4096
#define DC 22
#define NBLK 256
#define LRP 1040   // enc panel LDS row: 1024 + 16 u16 pad
#define LW  2056   // dec panel LDS row: 2048 + 8 u16 pad (2-way bank alias only)

typedef unsigned short u16;
typedef u16 u16x8 __attribute__((ext_vector_type(8)));
typedef __bf16 bf16x8 __attribute__((ext_vector_type(8)));
typedef float f32x4 __attribute__((ext_vector_type(4)));

__device__ __forceinline__ float sigm(float x) { return 1.f / (1.f + __expf(-x)); }

__device__ __forceinline__ u16 f2b(float v) {
  unsigned u = __float_as_uint(v);
  return (u16)((u + 0x7FFFu + ((u >> 16) & 1u)) >> 16);
}
__device__ __forceinline__ float b2f(u16 h) {
  return __uint_as_float(((unsigned)h) << 16);
}
__device__ __forceinline__ void store_b4(u16* __restrict__ d, size_t o, float4 v) {
  ushort4 s;
  s.x = f2b(v.x); s.y = f2b(v.y); s.z = f2b(v.z); s.w = f2b(v.w);
  *(ushort4*)(d + o) = s;
}

// ---------- device-wide barrier: RELAXED polling (no per-poll L2 invalidate!) ----------
__device__ __forceinline__ void gridbar(int* __restrict__ cnt, int* __restrict__ gen) {
  __syncthreads();
  if (threadIdx.x == 0) {
    int g = __hip_atomic_load(gen, __ATOMIC_RELAXED, __HIP_MEMORY_SCOPE_AGENT);
    int old = __hip_atomic_fetch_add(cnt, 1, __ATOMIC_ACQ_REL, __HIP_MEMORY_SCOPE_AGENT);
    if (old == NBLK - 1) {
      __hip_atomic_store(cnt, 0, __ATOMIC_RELAXED, __HIP_MEMORY_SCOPE_AGENT);
      __hip_atomic_store(gen, g + 1, __ATOMIC_RELEASE, __HIP_MEMORY_SCOPE_AGENT);
    } else {
      while (__hip_atomic_load(gen, __ATOMIC_RELAXED, __HIP_MEMORY_SCOPE_AGENT) == g)
        __builtin_amdgcn_s_sleep(4);
      (void)__hip_atomic_load(gen, __ATOMIC_ACQUIRE, __HIP_MEMORY_SCOPE_AGENT); // one inv
    }
  }
  __syncthreads();
}

// ---------- big parallel GEMM; W = bn-group width (4: keeps 4 B-panels L2-resident) ----------
template <int OUTBF>
__global__ __launch_bounds__(256) void gemm_bt(
    const u16* __restrict__ A1, long lda1, int K1,
    const u16* __restrict__ A2, long lda2,
    const u16* __restrict__ B, long ldb, const float* __restrict__ bias,
    void* __restrict__ Cp, long ldc, int M, int N, int K, int W)
{
  constexpr int LR = 72;
  __shared__ __align__(16) u16 sA[64 * LR];
  __shared__ __align__(16) u16 sB[128 * LR];
  const int tid = threadIdx.x, lane = tid & 63;
  const int wid = tid >> 6, wm = wid >> 1, wn = wid & 1;
  const int nbm = M >> 6;
  const int cpx = gridDim.x >> 3;
  const int swz = (blockIdx.x & 7) * cpx + (blockIdx.x >> 3);
  const int grpw = nbm * W;
  const int bn = (swz / grpw) * W + (swz % W);
  const int bm = (swz % grpw) / W;
  const size_t m0 = (size_t)bm << 6, n0 = (size_t)bn << 7;

  const int row = tid >> 3, c8 = tid & 7;
  u16x8 ra[2], rb[4];

  auto loadA = [&](int k0) {
    const u16* p; long lda; int kk;
    if (k0 < K1) { p = A1; lda = lda1; kk = k0; }
    else         { p = A2; lda = lda2; kk = k0 - K1; }
#pragma unroll
    for (int r = 0; r < 2; ++r)
      ra[r] = *(const u16x8*)(p + (m0 + row + r * 32) * (size_t)lda + (size_t)(kk + c8 * 8));
  };
  auto loadB = [&](int k0) {
#pragma unroll
    for (int r = 0; r < 4; ++r)
      rb[r] = *(const u16x8*)(B + (n0 + row + r * 32) * (size_t)ldb + (size_t)(k0 + c8 * 8));
  };
  loadA(0);
  loadB(0);

  f32x4 acc[2][4] = {};
  for (int k0 = 0; k0 < K; k0 += 64) {
    __syncthreads();
#pragma unroll
    for (int r = 0; r < 2; ++r) *(u16x8*)(sA + (row + r * 32) * LR + c8 * 8) = ra[r];
#pragma unroll
    for (int r = 0; r < 4; ++r) *(u16x8*)(sB + (row + r * 32) * LR + c8 * 8) = rb[r];
    __syncthreads();
    if (k0 + 64 < K) { loadA(k0 + 64); loadB(k0 + 64); }
#pragma unroll
    for (int ks = 0; ks < 2; ++ks) {
      const int ko = ks * 32 + (lane >> 4) * 8;
      bf16x8 af[2], bfr[4];
#pragma unroll
      for (int mi = 0; mi < 2; ++mi)
        af[mi] = *(const bf16x8*)(sA + ((wm << 5) + (mi << 4) + (lane & 15)) * LR + ko);
#pragma unroll
      for (int ni = 0; ni < 4; ++ni)
        bfr[ni] = *(const bf16x8*)(sB + ((wn << 6) + (ni << 4) + (lane & 15)) * LR + ko);
#pragma unroll
      for (int mi = 0; mi < 2; ++mi)
#pragma unroll
        for (int ni = 0; ni < 4; ++ni)
          acc[mi][ni] = __builtin_amdgcn_mfma_f32_16x16x32_bf16(af[mi], bfr[ni], acc[mi][ni], 0, 0, 0);
    }
  }

#pragma unroll
  for (int mi = 0; mi < 2; ++mi) {
    const int row0 = (wm << 5) + (mi << 4) + ((lane >> 4) << 2);
#pragma unroll
    for (int ni = 0; ni < 4; ++ni) {
      const size_t gn = n0 + (size_t)((wn << 6) + (ni << 4) + (lane & 15));
      const float bv = bias[gn];
#pragma unroll
      for (int r = 0; r < 4; ++r) {
        const size_t gm = m0 + (size_t)(row0 + r);
        const float v = acc[mi][ni][r] + bv;
        if (OUTBF) ((u16*)Cp)[gm * (size_t)ldc + gn] = f2b(v);
        else       ((float*)Cp)[gm * (size_t)ldc + gn] = v;
      }
    }
  }
}

// ---------- persistent encoder (perm64 layout, panel resident, c in regs) ----------
__global__ __launch_bounds__(512) void enc_persist(
    const u16* __restrict__ W, const u16* __restrict__ xg,
    u16* __restrict__ H, int* __restrict__ cnt, int* __restrict__ gen)
{
  __shared__ __align__(16) u16 sB[64 * LRP];
  const int tid = threadIdx.x, lane = tid & 63, w = tid >> 6;
  const int nblk = blockIdx.x >> 2, mg = blockIdx.x & 3;
  const int n0 = nblk << 6;
  const int l15 = lane & 15, l4 = lane >> 4;
  const int arow = mg * 128 + (w << 4) + l15;
  const int kof = l4 * 8;
  const int hg = (nblk << 4) | l15;
  const int row0 = mg * 128 + (w << 4) + (l4 << 2);

#pragma unroll
  for (int i = 0; i < 16; ++i) {
    const int c = i * 512 + tid, r = c >> 7, cc = c & 127;
    *(u16x8*)(sB + r * LRP + cc * 8) = *(const u16x8*)(W + (size_t)(n0 + r) * 1024 + cc * 8);
  }
  __syncthreads();

  f32x4 creg = {0.f, 0.f, 0.f, 0.f};
  for (int t = 0; t < DT; ++t) {
    f32x4 acc[4] = {};
    if (t > 0) {
      const u16* Ap = H + (size_t)(t - 1) * DB * DH + (size_t)arow * DH + kof;
      bf16x8 af = *(const bf16x8*)Ap;
      for (int ko = 0; ko < 1024; ko += 32) {
        bf16x8 afn = af;
        if (ko + 32 < 1024) afn = *(const bf16x8*)(Ap + ko + 32);
        bf16x8 b0 = *(const bf16x8*)(sB + (l15)      * LRP + ko + kof);
        bf16x8 b1 = *(const bf16x8*)(sB + (16 + l15) * LRP + ko + kof);
        bf16x8 b2 = *(const bf16x8*)(sB + (32 + l15) * LRP + ko + kof);
        bf16x8 b3 = *(const bf16x8*)(sB + (48 + l15) * LRP + ko + kof);
        acc[0] = __builtin_amdgcn_mfma_f32_16x16x32_bf16(af, b0, acc[0], 0, 0, 0);
        acc[1] = __builtin_amdgcn_mfma_f32_16x16x32_bf16(af, b1, acc[1], 0, 0, 0);
        acc[2] = __builtin_amdgcn_mfma_f32_16x16x32_bf16(af, b2, acc[2], 0, 0, 0);
        acc[3] = __builtin_amdgcn_mfma_f32_16x16x32_bf16(af, b3, acc[3], 0, 0, 0);
        af = afn;
      }
    }
    u16* Hw = H + (size_t)t * DB * DH;
#pragma unroll
    for (int r = 0; r < 4; ++r) {
      const int gm = row0 + r;
      const u16* xr = xg + ((size_t)gm * DT + t) * DG + n0 + l15;
      const float gi = acc[0][r] + b2f(xr[0]);
      const float gf = acc[1][r] + b2f(xr[16]);
      const float gg = acc[2][r] + b2f(xr[32]);
      const float go = acc[3][r] + b2f(xr[48]);
      const float cn = sigm(gf) * creg[r] + sigm(gi) * tanhf(gg);
      creg[r] = cn;
      Hw[(size_t)gm * DH + hg] = f2b(sigm(go) * tanhf(cn));
    }
    if (t < DT - 1) gridbar(cnt, gen);
  }
}

// ---------- persistent decoder: 32-col weight slice LDS-RESIDENT for all 26 steps ----------
// perm32: n' = ((h>>3)<<5)|(g<<3)|(h&7). Block = 256 rows x 32 gate-cols; 2 rowg x 128 colg.
// Epilogue: lanes j / j+8 exchange other-m-tile fragments via shfl_xor(8); lane j owns
// (h=j, m-tile 0), lane j+8 owns (h=j, m-tile 1). c in registers.
__global__ __launch_bounds__(512) void dec_persist(
    const u16* __restrict__ Wt, const u16* __restrict__ xg,
    const u16* __restrict__ projH,
    u16* __restrict__ Z0, u16* __restrict__ Z1,
    const float* __restrict__ clsW, const float* __restrict__ clsb,
    float* __restrict__ out, int* __restrict__ cnt, int* __restrict__ gen)
{
  __shared__ __align__(16) u16 sW[32 * LW];     // 131.6 KB
  __shared__ float red[2][DT][4];
  __shared__ float redc[2][DC][4];
  __shared__ float wgt[2][DT];
  const int tid = threadIdx.x, lane = tid & 63, w = tid >> 6;
  const int swz = (blockIdx.x & 7) * 32 + (blockIdx.x >> 3);
  const int colg = swz & 127, rowg = swz >> 7;
  const int n0 = colg << 5;
  const int mbase = rowg << 8;
  const int l15 = lane & 15, l4 = lane >> 4;
  const int sel = l15 >> 3, j = l15 & 7;
  const int hg = (colg << 3) + j;
  const int rowa = mbase + (w << 5);            // wave's 32-row base
  const int rr = tid >> 8, t4 = tid & 255, wv = (tid >> 6) & 3;
  const int b = 2 * swz + rr;

  // stage 32 x 2048 weight slice ONCE (consumed only after first gridbar's syncthreads)
#pragma unroll
  for (int i = 0; i < 16; ++i) {
    const int c = i * 512 + tid, r = c >> 8, cc = c & 255;
    *(u16x8*)(sW + r * LW + cc * 8) = *(const u16x8*)(Wt + (size_t)(n0 + r) * 2048 + cc * 8);
  }

  f32x4 creg = {0.f, 0.f, 0.f, 0.f};
  for (int t = 0; t < DT; ++t) {
    u16* Zin  = (t & 1) ? Z1 : Z0;
    u16* Zout = (t & 1) ? Z0 : Z1;

    // ---- attention (h = Zin.h) + classifier(t-1) ----
    ushort4 hz = *(const ushort4*)(Zin + ((size_t)b << 11) + 1024 + t4 * 4);
    float4 hv = make_float4(b2f(hz.x), b2f(hz.y), b2f(hz.z), b2f(hz.w));
    ushort4 ph[DT];
    float pp[DT];
#pragma unroll
    for (int tt = 0; tt < DT; ++tt) {
      ph[tt] = *(const ushort4*)(projH + (((size_t)tt * DB + b) << 10) + t4 * 4);
      pp[tt] = hv.x * b2f(ph[tt].x) + hv.y * b2f(ph[tt].y) +
               hv.z * b2f(ph[tt].z) + hv.w * b2f(ph[tt].w);
    }
#pragma unroll
    for (int tt = 0; tt < DT; ++tt) {
      float v = pp[tt];
#pragma unroll
      for (int off = 32; off; off >>= 1) v += __shfl_xor(v, off);
      if (lane == 0) red[rr][tt][wv] = v;
    }
    if (t > 0) {
#pragma unroll
      for (int c = 0; c < DC; ++c) {
        const float4 wc = *(const float4*)(clsW + ((size_t)c << 10) + t4 * 4);
        float v = hv.x * wc.x + hv.y * wc.y + hv.z * wc.z + hv.w * wc.w;
#pragma unroll
        for (int off = 32; off; off >>= 1) v += __shfl_xor(v, off);
        if (lane == 0) redc[rr][c][wv] = v;
      }
    }
    __syncthreads();
    if (t4 == 0) {
      float lg[DT], mx = -1e30f;
#pragma unroll
      for (int tt = 0; tt < DT; ++tt) {
        lg[tt] = (red[rr][tt][0] + red[rr][tt][1] + red[rr][tt][2] + red[rr][tt][3]) * 0.03125f;
        mx = fmaxf(mx, lg[tt]);
      }
      float s = 0.f;
#pragma unroll
      for (int tt = 0; tt < DT; ++tt) { lg[tt] = __expf(lg[tt] - mx); s += lg[tt]; }
      const float inv = 1.f / s;
#pragma unroll
      for (int tt = 0; tt < DT; ++tt) wgt[rr][tt] = lg[tt] * inv;
    }
    __syncthreads();
    if (t > 0 && t4 < DC)
      out[((size_t)b * DT + (t - 1)) * DC + t4] =
          redc[rr][t4][0] + redc[rr][t4][1] + redc[rr][t4][2] + redc[rr][t4][3] + clsb[t4];
    float4 a = make_float4(0, 0, 0, 0);
#pragma unroll
    for (int tt = 0; tt < DT; ++tt) {
      const float wt = wgt[rr][tt];
      a.x += wt * b2f(ph[tt].x); a.y += wt * b2f(ph[tt].y);
      a.z += wt * b2f(ph[tt].z); a.w += wt * b2f(ph[tt].w);
    }
    store_b4(Zin, ((size_t)b << 11) + t4 * 4, a);
    gridbar(cnt, gen);                           // attn visible; also fences sW staging

    // ---- gemm: A = Zin[256 rows x 2048], B = resident sW; full K always ----
    f32x4 acc[2][2] = {};
    const u16* Ap = Zin + (size_t)rowa * 2048;
#pragma unroll 4
    for (int k0 = 0; k0 < 2048; k0 += 32) {
      const int ko = k0 + l4 * 8;
      bf16x8 a0 = *(const bf16x8*)(Ap + (size_t)l15 * 2048 + ko);
      bf16x8 a1 = *(const bf16x8*)(Ap + (size_t)(16 + l15) * 2048 + ko);
      bf16x8 b0 = *(const bf16x8*)(sW + (l15)      * LW + ko);
      bf16x8 b1 = *(const bf16x8*)(sW + (16 + l15) * LW + ko);
      acc[0][0] = __builtin_amdgcn_mfma_f32_16x16x32_bf16(a0, b0, acc[0][0], 0, 0, 0);
      acc[0][1] = __builtin_amdgcn_mfma_f32_16x16x32_bf16(a0, b1, acc[0][1], 0, 0, 0);
      acc[1][0] = __builtin_amdgcn_mfma_f32_16x16x32_bf16(a1, b0, acc[1][0], 0, 0, 0);
      acc[1][1] = __builtin_amdgcn_mfma_f32_16x16x32_bf16(a1, b1, acc[1][1], 0, 0, 0);
    }

    // ---- epilogue: gate exchange + cell ----
    f32x4 own0 = acc[sel][0], own1 = acc[sel][1];
    f32x4 oth0 = acc[sel ^ 1][0], oth1 = acc[sel ^ 1][1];
    f32x4 r0, r1;
#pragma unroll
    for (int q = 0; q < 4; ++q) {
      r0[q] = __shfl_xor(oth0[q], 8);
      r1[q] = __shfl_xor(oth1[q], 8);
    }
    const f32x4 vi = sel ? r0 : own0;
    const f32x4 vf = sel ? own0 : r0;
    const f32x4 vg = sel ? r1 : own1;
    const f32x4 vo = sel ? own1 : r1;
    const int rbase = rowa + sel * 16 + l4 * 4;
#pragma unroll
    for (int r = 0; r < 4; ++r) {
      const int gm = rbase + r;
      const u16* xr = xg + ((size_t)gm * DT + t) * DG + n0;
      const float gi = vi[r] + b2f(xr[j]);
      const float gf = vf[r] + b2f(xr[8 + j]);
      const float gg = vg[r] + b2f(xr[16 + j]);
      const float go = vo[r] + b2f(xr[24 + j]);
      const float cn = sigm(gf) * creg[r] + sigm(gi) * tanhf(gg);
      creg[r] = cn;
      Zout[((size_t)gm << 11) + 1024 + hg] = f2b(sigm(go) * tanhf(cn));
    }
    gridbar(cnt, gen);                           // h_t visible before next attn
  }

  // final classifier on h_25 (DT even -> lives in Z0)
  {
    ushort4 hz = *(const ushort4*)(Z0 + ((size_t)b << 11) + 1024 + t4 * 4);
    float4 hv = make_float4(b2f(hz.x), b2f(hz.y), b2f(hz.z), b2f(hz.w));
#pragma unroll
    for (int c = 0; c < DC; ++c) {
      const float4 wc = *(const float4*)(clsW + ((size_t)c << 10) + t4 * 4);
      float v = hv.x * wc.x + hv.y * wc.y + hv.z * wc.z + hv.w * wc.w;
#pragma unroll
      for (int off = 32; off; off >>= 1) v += __shfl_xor(v, off);
      if (lane == 0) redc[rr][c][wv] = v;
    }
    __syncthreads();
    if (t4 < DC)
      out[((size_t)b * DT + (DT - 1)) * DC + t4] =
          redc[rr][t4][0] + redc[rr][t4][1] + redc[rr][t4][2] + redc[rr][t4][3] + clsb[t4];
  }
}

// ---------- packers ----------
__global__ __launch_bounds__(256) void cvt4_kernel(const float* __restrict__ src,
    u16* __restrict__ dst, int n4) {
  for (int i = blockIdx.x * 256 + threadIdx.x; i < n4; i += gridDim.x * 256) {
    float4 v = *(const float4*)(src + (size_t)i * 4);
    store_b4(dst, (size_t)i * 4, v);
  }
}

// gate-interleave pack; S=4: 64-wide groups (enc), S=3: 32-wide groups (dec)
__global__ __launch_bounds__(256) void pack_perm_kernel(const float* __restrict__ src,
    long ld_src, long scol, int cols4, u16* __restrict__ dst, long ld_dst, long dcol, int S) {
  const int total = DG * cols4;
  const int msk = (1 << S) - 1;
  for (int i = blockIdx.x * 256 + threadIdx.x; i < total; i += gridDim.x * 256) {
    const int np = i / cols4, c4 = i - np * cols4;
    const int g = (np >> S) & 3, h = ((np >> (S + 2)) << S) | (np & msk);
    const int n = g * 1024 + h;
    float4 v = *(const float4*)(src + (size_t)n * ld_src + scol + (size_t)c4 * 4);
    store_b4(dst, (size_t)np * ld_dst + dcol + (size_t)c4 * 4, v);
  }
}

__global__ void pack_bias_perm_kernel(const float* __restrict__ a,
    const float* __restrict__ b, float* __restrict__ o, int S) {
  int np = blockIdx.x * 256 + threadIdx.x;
  if (np < DG) {
    const int msk = (1 << S) - 1;
    const int g = (np >> S) & 3, h = ((np >> (S + 2)) << S) | (np & msk);
    const int n = g * 1024 + h;
    o[np] = a[n] + b[n];
  }
}

extern "C" void kernel_launch(void* const* d_in, const int* in_sizes, int n_in,
                              void* d_out, int out_size, void* d_ws, size_t ws_size,
                              hipStream_t stream) {
  const float* x    = (const float*)d_in[0];
  const float* eWih = (const float*)d_in[1];
  const float* eWhh = (const float*)d_in[2];
  const float* ebih = (const float*)d_in[3];
  const float* ebhh = (const float*)d_in[4];
  const float* pW   = (const float*)d_in[5];
  const float* pb   = (const float*)d_in[6];
  const float* dWih = (const float*)d_in[7];
  const float* dWhh = (const float*)d_in[8];
  const float* dbih = (const float*)d_in[9];
  const float* dbhh = (const float*)d_in[10];
  const float* clsW = (const float*)d_in[11];
  const float* clsb = (const float*)d_in[12];
  float* out = (float*)d_out;

  char* p = (char*)d_ws;
  auto alloc = [&](size_t bytes) -> void* {
    char* r = p; p += (bytes + 255) & ~(size_t)255; return (void*)r;
  };
  u16* Xb    = (u16*)alloc((size_t)DB * DT * DF * 2);        // 54.5 MB (reused as projHb)
  u16* eWx   = (u16*)alloc((size_t)DG * 2048 * 2);
  u16* eWh   = (u16*)alloc((size_t)DG * 1024 * 2);
  u16* dWx   = (u16*)alloc((size_t)DG * 2048 * 2);
  u16* dWah  = (u16*)alloc((size_t)DG * 2048 * 2);
  u16* pWb   = (u16*)alloc((size_t)DH * DH * 2);
  u16* Hb    = (u16*)alloc((size_t)DT * DB * DH * 2);
  u16* encXg = (u16*)alloc((size_t)DB * DT * DG * 2);        // 109 MB
  u16* decXg = (u16*)alloc((size_t)DB * DT * DG * 2);        // 109 MB
  u16* Z0    = (u16*)alloc((size_t)DB * 2048 * 2);
  u16* Z1    = (u16*)alloc((size_t)DB * 2048 * 2);
  float* ebs = (float*)alloc(DG * 4);
  float* dbs = (float*)alloc(DG * 4);
  int* bar   = (int*)alloc(256);
  u16* projHb = Xb;                                          // alias: Xb dead after decXg

  // ---- init / pack ----
  hipMemsetAsync(bar, 0, 256, stream);
  hipMemsetAsync(Z0, 0, (size_t)DB * 2048 * 2, stream);
  cvt4_kernel<<<2048, 256, 0, stream>>>(x, Xb, (int)((size_t)DB * DT * DF / 4));
  pack_perm_kernel<<<2048, 256, 0, stream>>>(eWih, DF, 0, DF / 4, eWx, 2048, 0, 4);
  pack_perm_kernel<<<2048, 256, 0, stream>>>(eWhh, DH, 0, DH / 4, eWh, 1024, 0, 4);
  pack_perm_kernel<<<2048, 256, 0, stream>>>(dWih, 3072, 0, DF / 4, dWx, 2048, 0, 3);
  pack_perm_kernel<<<2048, 256, 0, stream>>>(dWih, 3072, 2048, DH / 4, dWah, 2048, 0, 3);
  pack_perm_kernel<<<2048, 256, 0, stream>>>(dWhh, DH, 0, DH / 4, dWah, 2048, 1024, 3);
  cvt4_kernel<<<1024, 256, 0, stream>>>(pW, pWb, DH * DH / 4);
  pack_bias_perm_kernel<<<16, 256, 0, stream>>>(ebih, ebhh, ebs, 4);
  pack_bias_perm_kernel<<<16, 256, 0, stream>>>(dbih, dbhh, dbs, 3);

  // ---- hoisted x-gate GEMMs (bn-groups of 4 stay L2-resident per bm sweep) ----
  gemm_bt<1><<<6656, 256, 0, stream>>>(
      Xb, DF, DF, Xb, DF, eWx, DF, ebs, encXg, DG, DB * DT, DG, DF, 4);
  gemm_bt<1><<<6656, 256, 0, stream>>>(
      Xb, DF, DF, Xb, DF, dWx, DF, dbs, decXg, DG, DB * DT, DG, DF, 4);

  // ---- persistent encoder ----
  enc_persist<<<NBLK, 512, 0, stream>>>(eWh, encXg, Hb, bar, bar + 64);

  // ---- projection of all encoder states ----
  gemm_bt<1><<<1664, 256, 0, stream>>>(
      Hb, DH, DH, Hb, DH, pWb, DH, pb, projHb, DH, DT * DB, DH, DH, 1);

  // ---- persistent decoder ----
  dec_persist<<<NBLK, 512, 0, stream>>>(
      dWah, decXg, projHb, Z0, Z1, clsW, clsb, out, bar, bar + 64);
}

// Round 11
// 2855.719 us; speedup vs baseline: 1.4608x; 1.1498x over previous
//
#include <hip/hip_runtime.h>

#define DB 512
#define DT 26
#define DF 2048
#define DH 1024
#define DG 4096
#define DC 22
#define NBLK 256
#define LRP 1040   // enc panel LDS row: 1024 + 16 u16 pad
#define LW  2056   // dec panel LDS row: 2048 + 8 u16 pad

typedef unsigned short u16;
typedef u16 u16x8 __attribute__((ext_vector_type(8)));
typedef __bf16 bf16x8 __attribute__((ext_vector_type(8)));
typedef float f32x4 __attribute__((ext_vector_type(4)));
typedef unsigned u32x2 __attribute__((ext_vector_type(2)));

#define MFMA(a, b, c) __builtin_amdgcn_mfma_f32_16x16x32_bf16((a), (b), (c), 0, 0, 0)

__device__ __forceinline__ float sigm(float x) { return 1.f / (1.f + __expf(-x)); }

__device__ __forceinline__ u16 f2b(float v) {
  unsigned u = __float_as_uint(v);
  return (u16)((u + 0x7FFFu + ((u >> 16) & 1u)) >> 16);
}
__device__ __forceinline__ float b2f(u16 h) {
  return __uint_as_float(((unsigned)h) << 16);
}
__device__ __forceinline__ void store_b4(u16* __restrict__ d, size_t o, float4 v) {
  ushort4 s;
  s.x = f2b(v.x); s.y = f2b(v.y); s.z = f2b(v.z); s.w = f2b(v.w);
  *(ushort4*)(d + o) = s;
}

// ---------- agent-scope (sc1) memory ops: bypass L2, write-through to L3 ----------
__device__ __forceinline__ void ldg128_sc1(bf16x8& d, const u16* p) {
  asm volatile("global_load_dwordx4 %0, %1, off sc1" : "=v"(d) : "v"(p));
}
__device__ __forceinline__ u32x2 ldg64_sc1_sync(const void* p) {
  u32x2 r;
  asm volatile("global_load_dwordx2 %0, %1, off sc1\ns_waitcnt vmcnt(0)"
               : "=v"(r) : "v"(p) : "memory");
  return r;
}
__device__ __forceinline__ void stg16_sc1(u16* p, unsigned v) {
  asm volatile("global_store_short %0, %1, off sc1" :: "v"(p), "v"(v) : "memory");
}
__device__ __forceinline__ void stg64_sc1(void* p, u32x2 v) {
  asm volatile("global_store_dwordx2 %0, %1, off sc1" :: "v"(p), "v"(v) : "memory");
}

// ---------- device-wide barrier: parallel flags, no acquire/inv anywhere ----------
__device__ __forceinline__ void flagbar(int* __restrict__ flags, int* __restrict__ gen,
                                        int tag) {
  asm volatile("s_waitcnt vmcnt(0)" ::: "memory");   // all sc1 stores acked (in L3)
  __syncthreads();
  if (threadIdx.x == 0)
    __hip_atomic_store(&flags[blockIdx.x], tag, __ATOMIC_RELEASE, __HIP_MEMORY_SCOPE_AGENT);
  if (blockIdx.x == 0) {
    if (threadIdx.x < 64) {
#pragma unroll
      for (int i = 0; i < NBLK / 64; ++i) {
        while (__hip_atomic_load(&flags[threadIdx.x + i * 64], __ATOMIC_RELAXED,
                                 __HIP_MEMORY_SCOPE_AGENT) < tag)
          __builtin_amdgcn_s_sleep(1);
      }
    }
    __syncthreads();
    if (threadIdx.x == 0)
      __hip_atomic_store(gen, tag, __ATOMIC_RELEASE, __HIP_MEMORY_SCOPE_AGENT);
  }
  if (threadIdx.x == 0) {
    while (__hip_atomic_load(gen, __ATOMIC_RELAXED, __HIP_MEMORY_SCOPE_AGENT) < tag)
      __builtin_amdgcn_s_sleep(1);
  }
  __syncthreads();
}

// ---------- big parallel GEMM (round-4/7 proven) ----------
template <int OUTBF>
__global__ __launch_bounds__(256) void gemm_bt(
    const u16* __restrict__ A1, long lda1, int K1,
    const u16* __restrict__ A2, long lda2,
    const u16* __restrict__ B, long ldb, const float* __restrict__ bias,
    void* __restrict__ Cp, long ldc, int M, int N, int K, int W)
{
  constexpr int LR = 72;
  __shared__ __align__(16) u16 sA[64 * LR];
  __shared__ __align__(16) u16 sB[128 * LR];
  const int tid = threadIdx.x, lane = tid & 63;
  const int wid = tid >> 6, wm = wid >> 1, wn = wid & 1;
  const int nbm = M >> 6;
  const int cpx = gridDim.x >> 3;
  const int swz = (blockIdx.x & 7) * cpx + (blockIdx.x >> 3);
  const int grpw = nbm * W;
  const int bn = (swz / grpw) * W + (swz % W);
  const int bm = (swz % grpw) / W;
  const size_t m0 = (size_t)bm << 6, n0 = (size_t)bn << 7;

  const int row = tid >> 3, c8 = tid & 7;
  u16x8 ra[2], rb[4];

  auto loadA = [&](int k0) {
    const u16* p; long lda; int kk;
    if (k0 < K1) { p = A1; lda = lda1; kk = k0; }
    else         { p = A2; lda = lda2; kk = k0 - K1; }
#pragma unroll
    for (int r = 0; r < 2; ++r)
      ra[r] = *(const u16x8*)(p + (m0 + row + r * 32) * (size_t)lda + (size_t)(kk + c8 * 8));
  };
  auto loadB = [&](int k0) {
#pragma unroll
    for (int r = 0; r < 4; ++r)
      rb[r] = *(const u16x8*)(B + (n0 + row + r * 32) * (size_t)ldb + (size_t)(k0 + c8 * 8));
  };
  loadA(0);
  loadB(0);

  f32x4 acc[2][4] = {};
  for (int k0 = 0; k0 < K; k0 += 64) {
    __syncthreads();
#pragma unroll
    for (int r = 0; r < 2; ++r) *(u16x8*)(sA + (row + r * 32) * LR + c8 * 8) = ra[r];
#pragma unroll
    for (int r = 0; r < 4; ++r) *(u16x8*)(sB + (row + r * 32) * LR + c8 * 8) = rb[r];
    __syncthreads();
    if (k0 + 64 < K) { loadA(k0 + 64); loadB(k0 + 64); }
#pragma unroll
    for (int ks = 0; ks < 2; ++ks) {
      const int ko = ks * 32 + (lane >> 4) * 8;
      bf16x8 af[2], bfr[4];
#pragma unroll
      for (int mi = 0; mi < 2; ++mi)
        af[mi] = *(const bf16x8*)(sA + ((wm << 5) + (mi << 4) + (lane & 15)) * LR + ko);
#pragma unroll
      for (int ni = 0; ni < 4; ++ni)
        bfr[ni] = *(const bf16x8*)(sB + ((wn << 6) + (ni << 4) + (lane & 15)) * LR + ko);
#pragma unroll
      for (int mi = 0; mi < 2; ++mi)
#pragma unroll
        for (int ni = 0; ni < 4; ++ni)
          acc[mi][ni] = MFMA(af[mi], bfr[ni], acc[mi][ni]);
    }
  }

#pragma unroll
  for (int mi = 0; mi < 2; ++mi) {
    const int row0 = (wm << 5) + (mi << 4) + ((lane >> 4) << 2);
#pragma unroll
    for (int ni = 0; ni < 4; ++ni) {
      const size_t gn = n0 + (size_t)((wn << 6) + (ni << 4) + (lane & 15));
      const float bv = bias[gn];
#pragma unroll
      for (int r = 0; r < 4; ++r) {
        const size_t gm = m0 + (size_t)(row0 + r);
        const float v = acc[mi][ni][r] + bv;
        if (OUTBF) ((u16*)Cp)[gm * (size_t)ldc + gn] = f2b(v);
        else       ((float*)Cp)[gm * (size_t)ldc + gn] = v;
      }
    }
  }
}

// ---------- persistent encoder: panel resident, c in regs, pipelined sc1 A-loads ----------
__global__ __launch_bounds__(512, 2) void enc_persist(
    const u16* __restrict__ W, const u16* __restrict__ xg,
    u16* __restrict__ H, int* __restrict__ flags, int* __restrict__ gen)
{
  __shared__ __align__(16) u16 sB[64 * LRP];
  const int tid = threadIdx.x, lane = tid & 63;
  const int nblk = blockIdx.x >> 2, mg = blockIdx.x & 3;
  const int n0 = nblk << 6;
  const int l15 = lane & 15, l4 = lane >> 4;
  const int arow = mg * 128 + ((tid >> 6) << 4) + l15;
  const int kof = l4 * 8;
  const int hg = (nblk << 4) | l15;
  const int row0 = mg * 128 + ((tid >> 6) << 4) + (l4 << 2);

#pragma unroll
  for (int i = 0; i < 16; ++i) {
    const int c = i * 512 + tid, r = c >> 7, cc = c & 127;
    *(u16x8*)(sB + r * LRP + cc * 8) = *(const u16x8*)(W + (size_t)(n0 + r) * 1024 + cc * 8);
  }
  __syncthreads();

  f32x4 creg = {0.f, 0.f, 0.f, 0.f};
  for (int t = 0; t < DT; ++t) {
    // prefetch xg operands (read-only -> cached loads, waited at use)
    u16 xv[4][4];
#pragma unroll
    for (int r = 0; r < 4; ++r) {
      const u16* xr = xg + ((size_t)(row0 + r) * DT + t) * DG + n0 + l15;
      xv[r][0] = xr[0]; xv[r][1] = xr[16]; xv[r][2] = xr[32]; xv[r][3] = xr[48];
    }
    f32x4 a0 = {}, a1 = {}, a2 = {}, a3 = {};
    if (t > 0) {
      const u16* Ap = H + (size_t)(t - 1) * DB * DH + (size_t)arow * DH + kof;
      bf16x8 pA[8], qA[8];
#define E_ISSUE(B, gg) { _Pragma("unroll") \
      for (int i = 0; i < 8; ++i) ldg128_sc1(B[i], Ap + (gg) * 256 + i * 32); }
#define E_CONSUME(B, gg) { _Pragma("unroll") \
      for (int i = 0; i < 8; ++i) { \
        const int ko = (gg) * 256 + i * 32 + kof; \
        bf16x8 b0 = *(const bf16x8*)(sB + (l15)      * LRP + ko); \
        bf16x8 b1 = *(const bf16x8*)(sB + (16 + l15) * LRP + ko); \
        bf16x8 b2 = *(const bf16x8*)(sB + (32 + l15) * LRP + ko); \
        bf16x8 b3 = *(const bf16x8*)(sB + (48 + l15) * LRP + ko); \
        a0 = MFMA(B[i], b0, a0); a1 = MFMA(B[i], b1, a1); \
        a2 = MFMA(B[i], b2, a2); a3 = MFMA(B[i], b3, a3); } }
      E_ISSUE(pA, 0)
      E_ISSUE(qA, 1)
#pragma unroll
      for (int g = 0; g < 4; ++g) {
        if (g < 3) asm volatile("s_waitcnt vmcnt(8)" ::: "memory");
        else       asm volatile("s_waitcnt vmcnt(0)" ::: "memory");
        __builtin_amdgcn_sched_barrier(0);
        if ((g & 1) == 0) { E_CONSUME(pA, g) if (g < 2) E_ISSUE(pA, g + 2) }
        else              { E_CONSUME(qA, g) if (g < 2) E_ISSUE(qA, g + 2) }
      }
    }
    u16* Hw = H + (size_t)t * DB * DH;
#pragma unroll
    for (int r = 0; r < 4; ++r) {
      const float gi = a0[r] + b2f(xv[r][0]);
      const float gf = a1[r] + b2f(xv[r][1]);
      const float gg = a2[r] + b2f(xv[r][2]);
      const float go = a3[r] + b2f(xv[r][3]);
      const float cn = sigm(gf) * creg[r] + sigm(gi) * tanhf(gg);
      creg[r] = cn;
      stg16_sc1(Hw + (size_t)(row0 + r) * DH + hg, (unsigned)f2b(sigm(go) * tanhf(cn)));
    }
    if (t < DT - 1) flagbar(flags, gen, t + 1);
  }
}

// ---------- persistent decoder: weights LDS-resident, attn+cls fused, 2 bars/step ----------
__global__ __launch_bounds__(512, 2) void dec_persist(
    const u16* __restrict__ Wt, const u16* __restrict__ xg,
    const u16* __restrict__ projH,
    u16* __restrict__ Z0, u16* __restrict__ Z1,
    const float* __restrict__ clsW, const float* __restrict__ clsb,
    float* __restrict__ out, int* __restrict__ flags, int* __restrict__ gen, int tbase)
{
  __shared__ __align__(16) u16 sW[32 * LW];
  __shared__ float red[2][DT][4];
  __shared__ float redc[2][DC][4];
  __shared__ float wgt[2][DT];
  const int tid = threadIdx.x, lane = tid & 63, w = tid >> 6;
  const int swz = (blockIdx.x & 7) * 32 + (blockIdx.x >> 3);
  const int colg = swz & 127, rowg = swz >> 7;
  const int n0 = colg << 5;
  const int l15 = lane & 15, l4 = lane >> 4;
  const int kof = l4 * 8;
  const int sel = l15 >> 3, j = l15 & 7;
  const int hg = (colg << 3) + j;
  const int rowa = (rowg << 8) + (w << 5);
  const int rr = tid >> 8, t4 = tid & 255, wv = (tid >> 6) & 3;
  const int b = 2 * swz + rr;

#pragma unroll
  for (int i = 0; i < 16; ++i) {
    const int c = i * 512 + tid, r = c >> 8, cc = c & 255;
    *(u16x8*)(sW + r * LW + cc * 8) = *(const u16x8*)(Wt + (size_t)(n0 + r) * 2048 + cc * 8);
  }

  f32x4 creg = {0.f, 0.f, 0.f, 0.f};
  for (int t = 0; t < DT; ++t) {
    u16* Zin  = (t & 1) ? Z1 : Z0;
    u16* Zout = (t & 1) ? Z0 : Z1;

    // ---- attention (h from Zin.h, sc1) + classifier(t-1) ----
    u32x2 hzv = ldg64_sc1_sync(Zin + ((size_t)b << 11) + 1024 + t4 * 4);
    float4 hv = make_float4(b2f((u16)(hzv.x & 0xffff)), b2f((u16)(hzv.x >> 16)),
                            b2f((u16)(hzv.y & 0xffff)), b2f((u16)(hzv.y >> 16)));
    ushort4 ph[DT];
    float pp[DT];
#pragma unroll
    for (int tt = 0; tt < DT; ++tt) {
      ph[tt] = *(const ushort4*)(projH + (((size_t)tt * DB + b) << 10) + t4 * 4);
      pp[tt] = hv.x * b2f(ph[tt].x) + hv.y * b2f(ph[tt].y) +
               hv.z * b2f(ph[tt].z) + hv.w * b2f(ph[tt].w);
    }
#pragma unroll
    for (int tt = 0; tt < DT; ++tt) {
      float v = pp[tt];
#pragma unroll
      for (int off = 32; off; off >>= 1) v += __shfl_xor(v, off);
      if (lane == 0) red[rr][tt][wv] = v;
    }
    if (t > 0) {
#pragma unroll
      for (int c = 0; c < DC; ++c) {
        const float4 wc = *(const float4*)(clsW + ((size_t)c << 10) + t4 * 4);
        float v = hv.x * wc.x + hv.y * wc.y + hv.z * wc.z + hv.w * wc.w;
#pragma unroll
        for (int off = 32; off; off >>= 1) v += __shfl_xor(v, off);
        if (lane == 0) redc[rr][c][wv] = v;
      }
    }
    __syncthreads();
    if (t4 == 0) {
      float lg[DT], mx = -1e30f;
#pragma unroll
      for (int tt = 0; tt < DT; ++tt) {
        lg[tt] = (red[rr][tt][0] + red[rr][tt][1] + red[rr][tt][2] + red[rr][tt][3]) * 0.03125f;
        mx = fmaxf(mx, lg[tt]);
      }
      float s = 0.f;
#pragma unroll
      for (int tt = 0; tt < DT; ++tt) { lg[tt] = __expf(lg[tt] - mx); s += lg[tt]; }
      const float inv = 1.f / s;
#pragma unroll
      for (int tt = 0; tt < DT; ++tt) wgt[rr][tt] = lg[tt] * inv;
    }
    __syncthreads();
    if (t > 0 && t4 < DC)
      out[((size_t)b * DT + (t - 1)) * DC + t4] =
          redc[rr][t4][0] + redc[rr][t4][1] + redc[rr][t4][2] + redc[rr][t4][3] + clsb[t4];
    float4 a = make_float4(0, 0, 0, 0);
#pragma unroll
    for (int tt = 0; tt < DT; ++tt) {
      const float wt = wgt[rr][tt];
      a.x += wt * b2f(ph[tt].x); a.y += wt * b2f(ph[tt].y);
      a.z += wt * b2f(ph[tt].z); a.w += wt * b2f(ph[tt].w);
    }
    u32x2 pk;
    pk.x = (unsigned)f2b(a.x) | ((unsigned)f2b(a.y) << 16);
    pk.y = (unsigned)f2b(a.z) | ((unsigned)f2b(a.w) << 16);
    stg64_sc1(Zin + ((size_t)b << 11) + t4 * 4, pk);
    flagbar(flags, gen, tbase + 2 * t + 1);

    // ---- GEMM: pipelined sc1 A-loads vs LDS-resident weights ----
    const int rbase = rowa + sel * 16 + l4 * 4;
    u16 xv[4][4];
#pragma unroll
    for (int r = 0; r < 4; ++r) {
      const u16* xr = xg + ((size_t)(rbase + r) * DT + t) * DG + n0;
      xv[r][0] = xr[j]; xv[r][1] = xr[8 + j]; xv[r][2] = xr[16 + j]; xv[r][3] = xr[24 + j];
    }
    f32x4 a00 = {}, a01 = {}, a10 = {}, a11 = {};
    const u16* A0 = Zin + (size_t)(rowa + l15) * 2048 + kof;
    const u16* A1 = Zin + (size_t)(rowa + 16 + l15) * 2048 + kof;
    bf16x8 pA0[8], pA1[8], qA0[8], qA1[8];
#define D_ISSUE(B0, B1, gg) { _Pragma("unroll") \
    for (int i = 0; i < 8; ++i) { \
      ldg128_sc1(B0[i], A0 + (gg) * 256 + i * 32); \
      ldg128_sc1(B1[i], A1 + (gg) * 256 + i * 32); } }
#define D_CONSUME(B0, B1, gg) { _Pragma("unroll") \
    for (int i = 0; i < 8; ++i) { \
      const int ko = (gg) * 256 + i * 32 + kof; \
      bf16x8 w0 = *(const bf16x8*)(sW + (l15)      * LW + ko); \
      bf16x8 w1 = *(const bf16x8*)(sW + (16 + l15) * LW + ko); \
      a00 = MFMA(B0[i], w0, a00); a01 = MFMA(B0[i], w1, a01); \
      a10 = MFMA(B1[i], w0, a10); a11 = MFMA(B1[i], w1, a11); } }
    D_ISSUE(pA0, pA1, 0)
    D_ISSUE(qA0, qA1, 1)
#pragma unroll
    for (int g = 0; g < 8; ++g) {
      if (g < 7) asm volatile("s_waitcnt vmcnt(16)" ::: "memory");
      else       asm volatile("s_waitcnt vmcnt(0)" ::: "memory");
      __builtin_amdgcn_sched_barrier(0);
      if ((g & 1) == 0) { D_CONSUME(pA0, pA1, g) if (g < 6) D_ISSUE(pA0, pA1, g + 2) }
      else              { D_CONSUME(qA0, qA1, g) if (g < 6) D_ISSUE(qA0, qA1, g + 2) }
    }

    // ---- epilogue: gate exchange + cell ----
    f32x4 own0 = sel ? a10 : a00, own1 = sel ? a11 : a01;
    f32x4 oth0 = sel ? a00 : a10, oth1 = sel ? a01 : a11;
    f32x4 r0, r1;
#pragma unroll
    for (int q = 0; q < 4; ++q) {
      r0[q] = __shfl_xor(oth0[q], 8);
      r1[q] = __shfl_xor(oth1[q], 8);
    }
    const f32x4 vi = sel ? r0 : own0;
    const f32x4 vf = sel ? own0 : r0;
    const f32x4 vg = sel ? r1 : own1;
    const f32x4 vo = sel ? own1 : r1;
#pragma unroll
    for (int r = 0; r < 4; ++r) {
      const int gm = rbase + r;
      const float gi = vi[r] + b2f(xv[r][0]);
      const float gf = vf[r] + b2f(xv[r][1]);
      const float gg = vg[r] + b2f(xv[r][2]);
      const float go = vo[r] + b2f(xv[r][3]);
      const float cn = sigm(gf) * creg[r] + sigm(gi) * tanhf(gg);
      creg[r] = cn;
      stg16_sc1(Zout + ((size_t)gm << 11) + 1024 + hg, (unsigned)f2b(sigm(go) * tanhf(cn)));
    }
    flagbar(flags, gen, tbase + 2 * t + 2);
  }

  // final classifier on h_25 (DT even -> lives in Z0)
  {
    u32x2 hzv = ldg64_sc1_sync(Z0 + ((size_t)b << 11) + 1024 + t4 * 4);
    float4 hv = make_float4(b2f((u16)(hzv.x & 0xffff)), b2f((u16)(hzv.x >> 16)),
                            b2f((u16)(hzv.y & 0xffff)), b2f((u16)(hzv.y >> 16)));
#pragma unroll
    for (int c = 0; c < DC; ++c) {
      const float4 wc = *(const float4*)(clsW + ((size_t)c << 10) + t4 * 4);
      float v = hv.x * wc.x + hv.y * wc.y + hv.z * wc.z + hv.w * wc.w;
#pragma unroll
      for (int off = 32; off; off >>= 1) v += __shfl_xor(v, off);
      if (lane == 0) redc[rr][c][wv] = v;
    }
    __syncthreads();
    if (t4 < DC)
      out[((size_t)b * DT + (DT - 1)) * DC + t4] =
          redc[rr][t4][0] + redc[rr][t4][1] + redc[rr][t4][2] + redc[rr][t4][3] + clsb[t4];
  }
}

// ---------- packers ----------
__global__ __launch_bounds__(256) void cvt4_kernel(const float* __restrict__ src,
    u16* __restrict__ dst, int n4) {
  for (int i = blockIdx.x * 256 + threadIdx.x; i < n4; i += gridDim.x * 256) {
    float4 v = *(const float4*)(src + (size_t)i * 4);
    store_b4(dst, (size_t)i * 4, v);
  }
}

__global__ __launch_bounds__(256) void pack_perm_kernel(const float* __restrict__ src,
    long ld_src, long scol, int cols4, u16* __restrict__ dst, long ld_dst, long dcol, int S) {
  const int total = DG * cols4;
  const int msk = (1 << S) - 1;
  for (int i = blockIdx.x * 256 + threadIdx.x; i < total; i += gridDim.x * 256) {
    const int np = i / cols4, c4 = i - np * cols4;
    const int g = (np >> S) & 3, h = ((np >> (S + 2)) << S) | (np & msk);
    const int n = g * 1024 + h;
    float4 v = *(const float4*)(src + (size_t)n * ld_src + scol + (size_t)c4 * 4);
    store_b4(dst, (size_t)np * ld_dst + dcol + (size_t)c4 * 4, v);
  }
}

__global__ void pack_bias_perm_kernel(const float* __restrict__ a,
    const float* __restrict__ b, float* __restrict__ o, int S) {
  int np = blockIdx.x * 256 + threadIdx.x;
  if (np < DG) {
    const int msk = (1 << S) - 1;
    const int g = (np >> S) & 3, h = ((np >> (S + 2)) << S) | (np & msk);
    const int n = g * 1024 + h;
    o[np] = a[n] + b[n];
  }
}

extern "C" void kernel_launch(void* const* d_in, const int* in_sizes, int n_in,
                              void* d_out, int out_size, void* d_ws, size_t ws_size,
                              hipStream_t stream) {
  const float* x    = (const float*)d_in[0];
  const float* eWih = (const float*)d_in[1];
  const float* eWhh = (const float*)d_in[2];
  const float* ebih = (const float*)d_in[3];
  const float* ebhh = (const float*)d_in[4];
  const float* pW   = (const float*)d_in[5];
  const float* pb   = (const float*)d_in[6];
  const float* dWih = (const float*)d_in[7];
  const float* dWhh = (const float*)d_in[8];
  const float* dbih = (const float*)d_in[9];
  const float* dbhh = (const float*)d_in[10];
  const float* clsW = (const float*)d_in[11];
  const float* clsb = (const float*)d_in[12];
  float* out = (float*)d_out;

  char* p = (char*)d_ws;
  auto alloc = [&](size_t bytes) -> void* {
    char* r = p; p += (bytes + 255) & ~(size_t)255; return (void*)r;
  };
  u16* Xb    = (u16*)alloc((size_t)DB * DT * DF * 2);        // 54.5 MB (reused as projHb)
  u16* eWx   = (u16*)alloc((size_t)DG * 2048 * 2);
  u16* eWh   = (u16*)alloc((size_t)DG * 1024 * 2);
  u16* dWx   = (u16*)alloc((size_t)DG * 2048 * 2);
  u16* dWah  = (u16*)alloc((size_t)DG * 2048 * 2);
  u16* pWb   = (u16*)alloc((size_t)DH * DH * 2);
  u16* Hb    = (u16*)alloc((size_t)DT * DB * DH * 2);
  u16* encXg = (u16*)alloc((size_t)DB * DT * DG * 2);        // 109 MB
  u16* decXg = (u16*)alloc((size_t)DB * DT * DG * 2);        // 109 MB
  u16* Z0    = (u16*)alloc((size_t)DB * 2048 * 2);
  u16* Z1    = (u16*)alloc((size_t)DB * 2048 * 2);
  float* ebs = (float*)alloc(DG * 4);
  float* dbs = (float*)alloc(DG * 4);
  int* bar   = (int*)alloc(2048);                            // flags[256] + gen
  u16* projHb = Xb;                                          // alias: Xb dead after decXg

  // ---- init / pack ----
  hipMemsetAsync(bar, 0, 2048, stream);
  hipMemsetAsync(Z0, 0, (size_t)DB * 2048 * 2, stream);
  cvt4_kernel<<<2048, 256, 0, stream>>>(x, Xb, (int)((size_t)DB * DT * DF / 4));
  pack_perm_kernel<<<2048, 256, 0, stream>>>(eWih, DF, 0, DF / 4, eWx, 2048, 0, 4);
  pack_perm_kernel<<<2048, 256, 0, stream>>>(eWhh, DH, 0, DH / 4, eWh, 1024, 0, 4);
  pack_perm_kernel<<<2048, 256, 0, stream>>>(dWih, 3072, 0, DF / 4, dWx, 2048, 0, 3);
  pack_perm_kernel<<<2048, 256, 0, stream>>>(dWih, 3072, 2048, DH / 4, dWah, 2048, 0, 3);
  pack_perm_kernel<<<2048, 256, 0, stream>>>(dWhh, DH, 0, DH / 4, dWah, 2048, 1024, 3);
  cvt4_kernel<<<1024, 256, 0, stream>>>(pW, pWb, DH * DH / 4);
  pack_bias_perm_kernel<<<16, 256, 0, stream>>>(ebih, ebhh, ebs, 4);
  pack_bias_perm_kernel<<<16, 256, 0, stream>>>(dbih, dbhh, dbs, 3);

  // ---- hoisted x-gate GEMMs ----
  gemm_bt<1><<<6656, 256, 0, stream>>>(
      Xb, DF, DF, Xb, DF, eWx, DF, ebs, encXg, DG, DB * DT, DG, DF, 4);
  gemm_bt<1><<<6656, 256, 0, stream>>>(
      Xb, DF, DF, Xb, DF, dWx, DF, dbs, decXg, DG, DB * DT, DG, DF, 4);

  // ---- persistent encoder (tags 1..25) ----
  enc_persist<<<NBLK, 512, 0, stream>>>(eWh, encXg, Hb, (int*)bar, (int*)bar + 256);

  // ---- projection of all encoder states ----
  gemm_bt<1><<<1664, 256, 0, stream>>>(
      Hb, DH, DH, Hb, DH, pWb, DH, pb, projHb, DH, DT * DB, DH, DH, 1);

  // ---- persistent decoder (tags 26..77) ----
  dec_persist<<<NBLK, 512, 0, stream>>>(
      dWah, decXg, projHb, Z0, Z1, clsW, clsb, out, (int*)bar, (int*)bar + 256, 25);
}

// Round 12
// 2139.911 us; speedup vs baseline: 1.9495x; 1.3345x over previous
//
#include <hip/hip_runtime.h>

#define DB 512
#define DT 26
#define DF 2048
#define DH 1024
#define DG 4096
#define DC 22

typedef unsigned short u16;
typedef u16 u16x8 __attribute__((ext_vector_type(8)));
typedef __bf16 bf16x8 __attribute__((ext_vector_type(8)));
typedef float f32x4 __attribute__((ext_vector_type(4)));

#define MFMA(a, b, c) __builtin_amdgcn_mfma_f32_16x16x32_bf16((a), (b), (c), 0, 0, 0)

__device__ __forceinline__ float sigm(float x) { return 1.f / (1.f + __expf(-x)); }

__device__ __forceinline__ u16 f2b(float v) {
  unsigned u = __float_as_uint(v);
  return (u16)((u + 0x7FFFu + ((u >> 16) & 1u)) >> 16);
}
__device__ __forceinline__ float b2f(u16 h) {
  return __uint_as_float(((unsigned)h) << 16);
}
__device__ __forceinline__ void store_b4(u16* __restrict__ d, size_t o, float4 v) {
  ushort4 s;
  s.x = f2b(v.x); s.y = f2b(v.y); s.z = f2b(v.z); s.w = f2b(v.w);
  *(ushort4*)(d + o) = s;
}

// ---------- big parallel GEMM; W = bn-group width per XCD chunk ----------
template <int OUTBF>
__global__ __launch_bounds__(256) void gemm_bt(
    const u16* __restrict__ A1, long lda1, int K1,
    const u16* __restrict__ A2, long lda2,
    const u16* __restrict__ B, long ldb, const float* __restrict__ bias,
    void* __restrict__ Cp, long ldc, int M, int N, int K, int W)
{
  constexpr int LR = 72;
  __shared__ __align__(16) u16 sA[64 * LR];
  __shared__ __align__(16) u16 sB[128 * LR];
  const int tid = threadIdx.x, lane = tid & 63;
  const int wid = tid >> 6, wm = wid >> 1, wn = wid & 1;
  const int nbm = M >> 6;
  const int cpx = gridDim.x >> 3;
  const int swz = (blockIdx.x & 7) * cpx + (blockIdx.x >> 3);
  const int grpw = nbm * W;
  const int bn = (swz / grpw) * W + (swz % W);
  const int bm = (swz % grpw) / W;
  const size_t m0 = (size_t)bm << 6, n0 = (size_t)bn << 7;

  const int row = tid >> 3, c8 = tid & 7;
  u16x8 ra[2], rb[4];

  auto loadA = [&](int k0) {
    const u16* p; long lda; int kk;
    if (k0 < K1) { p = A1; lda = lda1; kk = k0; }
    else         { p = A2; lda = lda2; kk = k0 - K1; }
#pragma unroll
    for (int r = 0; r < 2; ++r)
      ra[r] = *(const u16x8*)(p + (m0 + row + r * 32) * (size_t)lda + (size_t)(kk + c8 * 8));
  };
  auto loadB = [&](int k0) {
#pragma unroll
    for (int r = 0; r < 4; ++r)
      rb[r] = *(const u16x8*)(B + (n0 + row + r * 32) * (size_t)ldb + (size_t)(k0 + c8 * 8));
  };
  loadA(0);
  loadB(0);

  f32x4 acc[2][4] = {};
  for (int k0 = 0; k0 < K; k0 += 64) {
    __syncthreads();
#pragma unroll
    for (int r = 0; r < 2; ++r) *(u16x8*)(sA + (row + r * 32) * LR + c8 * 8) = ra[r];
#pragma unroll
    for (int r = 0; r < 4; ++r) *(u16x8*)(sB + (row + r * 32) * LR + c8 * 8) = rb[r];
    __syncthreads();
    if (k0 + 64 < K) { loadA(k0 + 64); loadB(k0 + 64); }
#pragma unroll
    for (int ks = 0; ks < 2; ++ks) {
      const int ko = ks * 32 + (lane >> 4) * 8;
      bf16x8 af[2], bfr[4];
#pragma unroll
      for (int mi = 0; mi < 2; ++mi)
        af[mi] = *(const bf16x8*)(sA + ((wm << 5) + (mi << 4) + (lane & 15)) * LR + ko);
#pragma unroll
      for (int ni = 0; ni < 4; ++ni)
        bfr[ni] = *(const bf16x8*)(sB + ((wn << 6) + (ni << 4) + (lane & 15)) * LR + ko);
#pragma unroll
      for (int mi = 0; mi < 2; ++mi)
#pragma unroll
        for (int ni = 0; ni < 4; ++ni)
          acc[mi][ni] = MFMA(af[mi], bfr[ni], acc[mi][ni]);
    }
  }

#pragma unroll
  for (int mi = 0; mi < 2; ++mi) {
    const int row0 = (wm << 5) + (mi << 4) + ((lane >> 4) << 2);
#pragma unroll
    for (int ni = 0; ni < 4; ++ni) {
      const size_t gn = n0 + (size_t)((wn << 6) + (ni << 4) + (lane & 15));
      const float bv = bias[gn];
#pragma unroll
      for (int r = 0; r < 4; ++r) {
        const size_t gm = m0 + (size_t)(row0 + r);
        const float v = acc[mi][ni][r] + bv;
        if (OUTBF) ((u16*)Cp)[gm * (size_t)ldc + gn] = f2b(v);
        else       ((float*)Cp)[gm * (size_t)ldc + gn] = v;
      }
    }
  }
}

// ---------- fused per-step GEMM + LSTM cell (round-4 proven; lda/ldb explicit) ----------
template <int DEC>
__global__ __launch_bounds__(512) void step_gemm(
    const u16* __restrict__ A, long lda, const u16* __restrict__ B, long ldb,
    const u16* __restrict__ xg, long ldxg, float* __restrict__ cst,
    u16* __restrict__ hout, int K, int first, int skipA)
{
  constexpr int LR = 72;
  __shared__ __align__(16) u16 sA[64 * LR];
  __shared__ __align__(16) u16 sB[128 * LR];
  const int tid = threadIdx.x, lane = tid & 63;
  const int wid = tid >> 6, wm = wid >> 1, wn = wid & 1;   // 4m x 2n
  const int cpx = gridDim.x >> 3;              // 32
  const int swz = (blockIdx.x & 7) * cpx + (blockIdx.x >> 3);
  const int bn = swz >> 3, bm = swz & 7;       // nbm = 8 (M=512)
  const size_t m0 = (size_t)bm << 6, n0 = (size_t)bn << 7;

  const int row = tid >> 3, c8 = tid & 7;
  u16x8 ra, rb[2];
  auto loadA = [&](int k0) {
    ra = *(const u16x8*)(A + (m0 + row) * (size_t)lda + (size_t)(k0 + c8 * 8));
  };
  auto loadB = [&](int k0) {
#pragma unroll
    for (int r = 0; r < 2; ++r)
      rb[r] = *(const u16x8*)(B + (n0 + row + r * 64) * (size_t)ldb + (size_t)(k0 + c8 * 8));
  };

  f32x4 acc[4] = {};
  if (!skipA) {
    loadA(0);
    loadB(0);
    for (int k0 = 0; k0 < K; k0 += 64) {
      __syncthreads();
      *(u16x8*)(sA + row * LR + c8 * 8) = ra;
#pragma unroll
      for (int r = 0; r < 2; ++r) *(u16x8*)(sB + (row + r * 64) * LR + c8 * 8) = rb[r];
      __syncthreads();
      if (k0 + 64 < K) { loadA(k0 + 64); loadB(k0 + 64); }
#pragma unroll
      for (int ks = 0; ks < 2; ++ks) {
        const int ko = ks * 32 + (lane >> 4) * 8;
        bf16x8 af, bfr[4];
        af = *(const bf16x8*)(sA + ((wm << 4) + (lane & 15)) * LR + ko);
#pragma unroll
        for (int ni = 0; ni < 4; ++ni)
          bfr[ni] = *(const bf16x8*)(sB + ((wn << 6) + (ni << 4) + (lane & 15)) * LR + ko);
#pragma unroll
        for (int ni = 0; ni < 4; ++ni)
          acc[ni] = MFMA(af, bfr[ni], acc[ni]);
      }
    }
  }

  const int l = lane & 15;
  const int hg = (bn << 5) + (wn << 4) + l;
  const int row0 = (wm << 4) + ((lane >> 4) << 2);
#pragma unroll
  for (int r = 0; r < 4; ++r) {
    const int gm = (int)m0 + row0 + r;
    const u16* xr = xg + (size_t)gm * ldxg + n0 + (wn << 6) + l;
    const float gi = acc[0][r] + b2f(xr[0]);
    const float gf = acc[1][r] + b2f(xr[16]);
    const float gg = acc[2][r] + b2f(xr[32]);
    const float go = acc[3][r] + b2f(xr[48]);
    const size_t ch = ((size_t)gm << 10) + hg;
    const float cp = first ? 0.f : cst[ch];
    const float cn = sigm(gf) * cp + sigm(gi) * tanhf(gg);
    const float hn = sigm(go) * tanhf(cn);
    cst[ch] = cn;
    if (DEC) hout[((size_t)gm << 11) + 1024 + hg] = f2b(hn);
    else     hout[((size_t)gm << 10) + hg] = f2b(hn);
  }
}

// ---------- packers ----------
__global__ __launch_bounds__(256) void cvt4_kernel(const float* __restrict__ src,
    u16* __restrict__ dst, int n4) {
  for (int i = blockIdx.x * 256 + threadIdx.x; i < n4; i += gridDim.x * 256) {
    float4 v = *(const float4*)(src + (size_t)i * 4);
    store_b4(dst, (size_t)i * 4, v);
  }
}

__global__ __launch_bounds__(256) void pack_perm_kernel(const float* __restrict__ src,
    long ld_src, long scol, int cols4, u16* __restrict__ dst, long ld_dst, long dcol) {
  const int total = DG * cols4;
  for (int i = blockIdx.x * 256 + threadIdx.x; i < total; i += gridDim.x * 256) {
    const int np = i / cols4, c4 = i - np * cols4;
    const int g = (np >> 4) & 3, h = ((np >> 6) << 4) | (np & 15);
    const int n = g * 1024 + h;
    float4 v = *(const float4*)(src + (size_t)n * ld_src + scol + (size_t)c4 * 4);
    store_b4(dst, (size_t)np * ld_dst + dcol + (size_t)c4 * 4, v);
  }
}

__global__ void pack_bias_perm_kernel(const float* __restrict__ a,
    const float* __restrict__ b, float* __restrict__ o) {
  int np = blockIdx.x * 256 + threadIdx.x;
  if (np < DG) {
    const int g = (np >> 4) & 3, h = ((np >> 6) << 4) | (np & 15);
    const int n = g * 1024 + h;
    o[np] = a[n] + b[n];
  }
}

// ---------- fused attention(t) + classifier(t-1); one block per batch row ----------
template <int DO_ATTN>
__global__ __launch_bounds__(256) void attn_cls_kernel(
    const u16* __restrict__ projH, const u16* __restrict__ Zr, u16* __restrict__ Zw,
    const float* __restrict__ clsW, const float* __restrict__ clsb,
    float* __restrict__ out, int do_cls, int tprev)
{
  const int b = blockIdx.x, tid = threadIdx.x, lane = tid & 63, wid = tid >> 6;
  __shared__ float redc[DC][4];
  __shared__ float red[DT][4];
  __shared__ float wgt[DT];

  ushort4 hz = *(const ushort4*)(Zr + ((size_t)b << 11) + 1024 + tid * 4);
  float4 hv = make_float4(b2f(hz.x), b2f(hz.y), b2f(hz.z), b2f(hz.w));

  if (do_cls) {
    float acc[DC];
#pragma unroll
    for (int c = 0; c < DC; ++c) {
      const float4 w = *(const float4*)(clsW + ((size_t)c << 10) + tid * 4);
      acc[c] = hv.x * w.x + hv.y * w.y + hv.z * w.z + hv.w * w.w;
    }
#pragma unroll
    for (int c = 0; c < DC; ++c) {
      float v = acc[c];
#pragma unroll
      for (int off = 32; off; off >>= 1) v += __shfl_xor(v, off);
      if (lane == 0) redc[c][wid] = v;
    }
  }

  if (DO_ATTN) {
    float ph[DT][4];
    float p[DT];
#pragma unroll
    for (int t = 0; t < DT; ++t) {
      ushort4 pv = *(const ushort4*)(projH + (((size_t)t * DB + b) << 10) + tid * 4);
      ph[t][0] = b2f(pv.x); ph[t][1] = b2f(pv.y); ph[t][2] = b2f(pv.z); ph[t][3] = b2f(pv.w);
      p[t] = hv.x * ph[t][0] + hv.y * ph[t][1] + hv.z * ph[t][2] + hv.w * ph[t][3];
    }
#pragma unroll
    for (int t = 0; t < DT; ++t) {
#pragma unroll
      for (int off = 32; off; off >>= 1) p[t] += __shfl_xor(p[t], off);
      if (lane == 0) red[t][wid] = p[t];
    }
    __syncthreads();
    if (tid == 0) {
      float lg[DT];
      float mx = -1e30f;
#pragma unroll
      for (int t = 0; t < DT; ++t) {
        lg[t] = (red[t][0] + red[t][1] + red[t][2] + red[t][3]) * 0.03125f;
        mx = fmaxf(mx, lg[t]);
      }
      float s = 0.f;
#pragma unroll
      for (int t = 0; t < DT; ++t) { lg[t] = __expf(lg[t] - mx); s += lg[t]; }
      float inv = 1.f / s;
#pragma unroll
      for (int t = 0; t < DT; ++t) wgt[t] = lg[t] * inv;
    }
    __syncthreads();
    float4 a = make_float4(0, 0, 0, 0);
#pragma unroll
    for (int t = 0; t < DT; ++t) {
      const float w = wgt[t];
      a.x += w * ph[t][0]; a.y += w * ph[t][1]; a.z += w * ph[t][2]; a.w += w * ph[t][3];
    }
    store_b4(Zw, ((size_t)b << 11) + tid * 4, a);
  }

  if (do_cls) {
    __syncthreads();
    if (tid < DC)
      out[((size_t)b * DT + tprev) * DC + tid] =
          redc[tid][0] + redc[tid][1] + redc[tid][2] + redc[tid][3] + clsb[tid];
  }
}

extern "C" void kernel_launch(void* const* d_in, const int* in_sizes, int n_in,
                              void* d_out, int out_size, void* d_ws, size_t ws_size,
                              hipStream_t stream) {
  const float* x    = (const float*)d_in[0];
  const float* eWih = (const float*)d_in[1];
  const float* eWhh = (const float*)d_in[2];
  const float* ebih = (const float*)d_in[3];
  const float* ebhh = (const float*)d_in[4];
  const float* pW   = (const float*)d_in[5];
  const float* pb   = (const float*)d_in[6];
  const float* dWih = (const float*)d_in[7];
  const float* dWhh = (const float*)d_in[8];
  const float* dbih = (const float*)d_in[9];
  const float* dbhh = (const float*)d_in[10];
  const float* clsW = (const float*)d_in[11];
  const float* clsb = (const float*)d_in[12];
  float* out = (float*)d_out;

  char* p = (char*)d_ws;
  auto alloc = [&](size_t bytes) -> void* {
    char* r = p; p += (bytes + 255) & ~(size_t)255; return (void*)r;
  };
  u16* Xb    = (u16*)alloc((size_t)DB * DT * DF * 2);        // 54.5 MB (reused as projHb)
  u16* eWx   = (u16*)alloc((size_t)DG * 2048 * 2);
  u16* eWh   = (u16*)alloc((size_t)DG * 1024 * 2);
  u16* dWx   = (u16*)alloc((size_t)DG * 2048 * 2);
  u16* dWah  = (u16*)alloc((size_t)DG * 2048 * 2);
  u16* pWb   = (u16*)alloc((size_t)DH * DH * 2);
  u16* Hb    = (u16*)alloc((size_t)DT * DB * DH * 2);
  u16* encXg = (u16*)alloc((size_t)DB * DT * DG * 2);        // 109 MB
  u16* decXg = (u16*)alloc((size_t)DB * DT * DG * 2);        // 109 MB
  u16* Z0    = (u16*)alloc((size_t)DB * 2048 * 2);
  u16* Z1    = (u16*)alloc((size_t)DB * 2048 * 2);
  float* eCs = (float*)alloc((size_t)DB * DH * 4);
  float* dCs = (float*)alloc((size_t)DB * DH * 4);
  float* ebs = (float*)alloc(DG * 4);
  float* dbs = (float*)alloc(DG * 4);
  u16* projHb = Xb;                                          // alias: Xb dead after decXg

  // ---- pack ----
  cvt4_kernel<<<2048, 256, 0, stream>>>(x, Xb, (int)((size_t)DB * DT * DF / 4));
  pack_perm_kernel<<<2048, 256, 0, stream>>>(eWih, DF, 0, DF / 4, eWx, 2048, 0);
  pack_perm_kernel<<<2048, 256, 0, stream>>>(eWhh, DH, 0, DH / 4, eWh, 1024, 0);
  pack_perm_kernel<<<2048, 256, 0, stream>>>(dWih, 3072, 0, DF / 4, dWx, 2048, 0);
  pack_perm_kernel<<<2048, 256, 0, stream>>>(dWih, 3072, 2048, DH / 4, dWah, 2048, 0);
  pack_perm_kernel<<<2048, 256, 0, stream>>>(dWhh, DH, 0, DH / 4, dWah, 2048, 1024);
  cvt4_kernel<<<1024, 256, 0, stream>>>(pW, pWb, DH * DH / 4);
  pack_bias_perm_kernel<<<16, 256, 0, stream>>>(ebih, ebhh, ebs);
  pack_bias_perm_kernel<<<16, 256, 0, stream>>>(dbih, dbhh, dbs);
  hipMemsetAsync(Z0, 0, (size_t)DB * 2048 * 2, stream);

  // ---- hoisted x-gate GEMMs: W=4 -> per XCD: 4 B-panels (2 MB) L2-resident, A streamed once ----
  gemm_bt<1><<<6656, 256, 0, stream>>>(
      Xb, DF, DF, Xb, DF, eWx, DF, ebs, encXg, DG, DB * DT, DG, DF, 4);
  gemm_bt<1><<<6656, 256, 0, stream>>>(
      Xb, DF, DF, Xb, DF, dWx, DF, dbs, decXg, DG, DB * DT, DG, DF, 4);

  // ---- encoder: fused gemm+cell per step (t=0: skip GEMM, h0==0) ----
  for (int t = 0; t < DT; ++t) {
    step_gemm<0><<<256, 512, 0, stream>>>(
        (t == 0) ? Hb : (Hb + (size_t)(t - 1) * DB * DH), DH, eWh, DH,
        encXg + (size_t)t * DG, (long)DT * DG, eCs,
        Hb + (size_t)t * DB * DH, 1024, t == 0, t == 0);
  }

  // ---- projection of all encoder states ----
  gemm_bt<1><<<1664, 256, 0, stream>>>(
      Hb, DH, DH, Hb, DH, pWb, DH, pb, projHb, DH, DT * DB, DH, DH, 1);

  // ---- decoder: attn(t)+cls(t-1), then fused gemm+cell (t=0: K=1024 attn cols only) ----
  for (int t = 0; t < DT; ++t) {
    u16* Zc = (t & 1) ? Z1 : Z0;
    u16* Zn = (t & 1) ? Z0 : Z1;
    attn_cls_kernel<1><<<DB, 256, 0, stream>>>(
        projHb, Zc, Zc, clsW, clsb, out, t > 0, t - 1);
    step_gemm<1><<<256, 512, 0, stream>>>(
        Zc, 2048, dWah, 2048, decXg + (size_t)t * DG, (long)DT * DG, dCs, Zn,
        (t == 0) ? 1024 : 2048, t == 0, 0);
  }
  // final classifier for h_25 (lives in Z0 after t=25)
  attn_cls_kernel<0><<<DB, 256, 0, stream>>>(
      projHb, Z0, Z0, clsW, clsb, out, 1, DT - 1);
}